// Round 2
// baseline (136.908 us; speedup 1.0000x reference)
//
#include <hip/hip_runtime.h>

#define NN 8192
#define FD 128

typedef float f32x4 __attribute__((ext_vector_type(4)));
typedef short short8 __attribute__((ext_vector_type(8)));
typedef unsigned short ushort4v __attribute__((ext_vector_type(4)));
typedef unsigned short ushort8v __attribute__((ext_vector_type(8)));

__device__ __forceinline__ unsigned short f2bf(float f) {
  unsigned int u = __builtin_bit_cast(unsigned int, f);
  u += 0x7fffu + ((u >> 16) & 1u);   // round-to-nearest-even
  return (unsigned short)(u >> 16);
}
__device__ __forceinline__ float bf2f(unsigned short h) {
  unsigned int u = ((unsigned int)h) << 16;
  return __builtin_bit_cast(float, u);
}

// -------- Kernel 1: xk = x@kern in bf16, stored transposed AND row-major ----
__global__ __launch_bounds__(256) void xk_kernel(
    const float* __restrict__ x, const float* __restrict__ kern,
    unsigned short* __restrict__ xkT, unsigned short* __restrict__ xk_rm) {
  __shared__ __align__(16) unsigned short kl[FD * FD];
  __shared__ __align__(16) float xl[16 * FD];
  const int t = threadIdx.x;
  const int row0 = blockIdx.x * 16;

  #pragma unroll
  for (int j = 0; j < 16; ++j) {
    int idx = (j * 256 + t) * 4;
    f32x4 kv = *(const f32x4*)&kern[idx];
    ushort4v kw;
    #pragma unroll
    for (int q = 0; q < 4; ++q) kw[q] = f2bf(kv[q]);
    *(ushort4v*)&kl[idx] = kw;
  }
  #pragma unroll
  for (int j = 0; j < 2; ++j) {
    int idx = (j * 256 + t) * 4;
    *(f32x4*)&xl[idx] = *(const f32x4*)&x[(size_t)row0 * FD + idx];
  }
  __syncthreads();

  const int r0 = (t >> 5) * 2;
  const int c0 = (t & 31) * 4;
  float acc[2][4] = {};
  #pragma unroll 4
  for (int k = 0; k < FD; ++k) {
    ushort4v kq = *(const ushort4v*)&kl[k * FD + c0];
    float kv[4];
    #pragma unroll
    for (int q = 0; q < 4; ++q) kv[q] = bf2f(kq[q]);
    float x0 = xl[r0 * FD + k];
    float x1 = xl[(r0 + 1) * FD + k];
    #pragma unroll
    for (int q = 0; q < 4; ++q) {
      acc[0][q] += x0 * kv[q];
      acc[1][q] += x1 * kv[q];
    }
  }
  #pragma unroll
  for (int i = 0; i < 2; ++i) {
    int r = row0 + r0 + i;
    ushort4v ow;
    #pragma unroll
    for (int q = 0; q < 4; ++q) {
      unsigned short b = f2bf(acc[i][q]);
      ow[q] = b;
      xkT[(size_t)(c0 + q) * NN + r] = b;      // transposed (B-operand layout)
    }
    *(ushort4v*)&xk_rm[(size_t)r * FD + c0] = ow;  // row-major (epilogue)
  }
}

// -------- Kernel 2: barrier-free split-K MFMA; wave owns 32 rows x 128 cols --
template <int S>
__global__ __launch_bounds__(256, 2) void gcn_mm(
    const float* __restrict__ adj, const unsigned short* __restrict__ xkT,
    float* __restrict__ parts, float* __restrict__ rowpart) {
  constexpr int KW = NN / S;       // K per wave
  constexpr int NIT = KW / 32;     // MFMA K-steps
  const int t = threadIdx.x;
  const int l = t & 63;
  const int w = blockIdx.x * 4 + (t >> 6);
  const int g = w / S;             // row-group (32 rows)
  const int s = w % S;             // K-slot
  const int row0 = g * 32;
  const int rl = l & 15;
  const int kb = s * KW + ((l >> 4) * 8);

  const float* pa0 = adj + (size_t)(row0 + rl) * NN + kb;
  const float* pa1 = pa0 + (size_t)16 * NN;
  const unsigned short* pb = xkT + (size_t)rl * NN + kb;

  f32x4 acc[2][8] = {};
  float rs0 = 0.f, rs1 = 0.f;

  f32x4 Ab[2][4];                  // depth-2 A prefetch (HBM)
  ushort8v Bb[2][8];               // depth-1 B prefetch (L2)

  Ab[0][0] = *(const f32x4*)(pa0);
  Ab[0][1] = *(const f32x4*)(pa0 + 4);
  Ab[0][2] = *(const f32x4*)(pa1);
  Ab[0][3] = *(const f32x4*)(pa1 + 4);
  Ab[1][0] = *(const f32x4*)(pa0 + 32);
  Ab[1][1] = *(const f32x4*)(pa0 + 36);
  Ab[1][2] = *(const f32x4*)(pa1 + 32);
  Ab[1][3] = *(const f32x4*)(pa1 + 36);
  #pragma unroll
  for (int c = 0; c < 8; ++c)
    Bb[0][c] = *(const ushort8v*)(pb + (size_t)c * 16 * NN);

  #pragma unroll 4
  for (int kt = 0; kt < NIT; ++kt) {
    const int cur = kt & 1;
    const int nxt = cur ^ 1;
    // 1. consume A[cur] -> bf16 frags + rowsum
    short8 a0, a1;
    #pragma unroll
    for (int h = 0; h < 2; ++h) {
      #pragma unroll
      for (int q = 0; q < 4; ++q) {
        float v0 = Ab[cur][h][q];
        float v1 = Ab[cur][2 + h][q];
        rs0 += v0;
        rs1 += v1;
        a0[h * 4 + q] = (short)f2bf(v0);
        a1[h * 4 + q] = (short)f2bf(v1);
      }
    }
    // 2. issue A loads for kt+2 into the just-freed buffer
    if (kt + 2 < NIT) {
      const int ko = (kt + 2) * 32;
      Ab[cur][0] = *(const f32x4*)(pa0 + ko);
      Ab[cur][1] = *(const f32x4*)(pa0 + ko + 4);
      Ab[cur][2] = *(const f32x4*)(pa1 + ko);
      Ab[cur][3] = *(const f32x4*)(pa1 + ko + 4);
    }
    // 3. issue B loads for kt+1
    if (kt + 1 < NIT) {
      const int ko = (kt + 1) * 32;
      #pragma unroll
      for (int c = 0; c < 8; ++c)
        Bb[nxt][c] = *(const ushort8v*)(pb + (size_t)c * 16 * NN + ko);
    }
    // 4. MFMAs on current tile
    #pragma unroll
    for (int c = 0; c < 8; ++c) {
      acc[0][c] = __builtin_amdgcn_mfma_f32_16x16x32_bf16(a0, Bb[cur][c], acc[0][c], 0, 0, 0);
      acc[1][c] = __builtin_amdgcn_mfma_f32_16x16x32_bf16(a1, Bb[cur][c], acc[1][c], 0, 0, 0);
    }
  }

  // rowsum: combine the 4 k-lane-groups (same row = l&15)
  rs0 += __shfl_xor(rs0, 16);
  rs0 += __shfl_xor(rs0, 32);
  rs1 += __shfl_xor(rs1, 16);
  rs1 += __shfl_xor(rs1, 32);
  if (l < 16) {
    rowpart[(size_t)s * NN + row0 + l] = rs0;
    rowpart[(size_t)s * NN + row0 + 16 + l] = rs1;
  }

  // store f32 partial tile: C/D layout col = l&15, row = (l>>4)*4 + j
  float* pp = parts + ((size_t)s * NN + row0) * FD;
  #pragma unroll
  for (int rf = 0; rf < 2; ++rf) {
    #pragma unroll
    for (int c = 0; c < 8; ++c) {
      #pragma unroll
      for (int j = 0; j < 4; ++j) {
        int r = rf * 16 + ((l >> 4) << 2) + j;
        pp[(size_t)r * FD + c * 16 + rl] = acc[rf][c][j];
      }
    }
  }
}

// -------- Kernel 3: reduce S partials + epilogue ---------------------------
__global__ __launch_bounds__(256) void gcn_fin(
    const float* __restrict__ parts, const float* __restrict__ rowpart,
    const unsigned short* __restrict__ xk_rm, const float* __restrict__ beta,
    const float* __restrict__ bias, float* __restrict__ out, int S) {
  const int t = threadIdx.x;
  const int r = blockIdx.x * 16 + (t >> 4);
  const int c0 = (t & 15) * 8;

  float rsum = 0.f;
  for (int s = 0; s < S; ++s) rsum += rowpart[(size_t)s * NN + r];
  const float bt = beta[r];
  const float inv = 1.0f / (rsum + bt);

  f32x4 acc0 = {0.f, 0.f, 0.f, 0.f};
  f32x4 acc1 = {0.f, 0.f, 0.f, 0.f};
  for (int s = 0; s < S; ++s) {
    const float* p = parts + ((size_t)s * NN + r) * FD + c0;
    acc0 += *(const f32x4*)p;
    acc1 += *(const f32x4*)(p + 4);
  }
  ushort8v xv = *(const ushort8v*)&xk_rm[(size_t)r * FD + c0];
  f32x4 o0, o1;
  #pragma unroll
  for (int q = 0; q < 4; ++q) {
    o0[q] = (acc0[q] + bt * bf2f(xv[q])) * inv + bias[c0 + q];
    o1[q] = (acc1[q] + bt * bf2f(xv[4 + q])) * inv + bias[c0 + 4 + q];
  }
  *(f32x4*)&out[(size_t)r * FD + c0] = o0;
  *(f32x4*)&out[(size_t)r * FD + c0 + 4] = o1;
}

extern "C" void kernel_launch(void* const* d_in, const int* in_sizes, int n_in,
                              void* d_out, int out_size, void* d_ws, size_t ws_size,
                              hipStream_t stream) {
  const float* x    = (const float*)d_in[0];
  const float* adj  = (const float*)d_in[1];
  const float* kern = (const float*)d_in[2];
  const float* bias = (const float*)d_in[3];
  const float* beta = (const float*)d_in[4];
  float* out = (float*)d_out;

  char* ws = (char*)d_ws;
  unsigned short* xkT   = (unsigned short*)ws;                       // 2 MB
  unsigned short* xk_rm = (unsigned short*)(ws + (size_t)NN * FD * 2);  // 2 MB
  size_t off_rowpart = (size_t)NN * FD * 4;
  float* rowpart = (float*)(ws + off_rowpart);                       // ≤256 KB
  size_t off_parts = off_rowpart + (size_t)8 * NN * 4;
  float* parts = (float*)(ws + off_parts);

  int S = 8;
  while (S > 1 && off_parts + (size_t)S * NN * FD * 4 > ws_size) S >>= 1;

  hipLaunchKernelGGL(xk_kernel, dim3(NN / 16), dim3(256), 0, stream,
                     x, kern, xkT, xk_rm);

  dim3 grid(64 * S), blk(256);
  switch (S) {
    case 8: hipLaunchKernelGGL(gcn_mm<8>, grid, blk, 0, stream, adj, xkT, parts, rowpart); break;
    case 4: hipLaunchKernelGGL(gcn_mm<4>, grid, blk, 0, stream, adj, xkT, parts, rowpart); break;
    case 2: hipLaunchKernelGGL(gcn_mm<2>, grid, blk, 0, stream, adj, xkT, parts, rowpart); break;
    default: hipLaunchKernelGGL(gcn_mm<1>, grid, blk, 0, stream, adj, xkT, parts, rowpart); break;
  }

  hipLaunchKernelGGL(gcn_fin, dim3(NN / 16), dim3(256), 0, stream,
                     parts, rowpart, xk_rm, beta, bias, out, S);
}

// Round 3
// 98.852 us; speedup vs baseline: 1.3850x; 1.3850x over previous
//
#include <hip/hip_runtime.h>

#define NN 8192
#define FD 128
#define BM 64
#define BK 64
#define LDS_ROW 72   // ushorts per LDS A row (144 B: pad -> conflict-free)

typedef float f32x4 __attribute__((ext_vector_type(4)));
typedef short short8 __attribute__((ext_vector_type(8)));
typedef unsigned short ushort4v __attribute__((ext_vector_type(4)));
typedef unsigned short ushort8v __attribute__((ext_vector_type(8)));

__device__ __forceinline__ unsigned short f2bf(float f) {
  unsigned int u = __builtin_bit_cast(unsigned int, f);
  u += 0x7fffu + ((u >> 16) & 1u);   // round-to-nearest-even
  return (unsigned short)(u >> 16);
}
__device__ __forceinline__ float bf2f(unsigned short h) {
  unsigned int u = ((unsigned int)h) << 16;
  return __builtin_bit_cast(float, u);
}

// -------- Kernel 1: xk = x@kern (bf16), emitted as MFMA B-fragments + row-major
// bfrag[((kt*8 + cb)*64 + lane)*8 + j] = xk[kt*32 + (lane>>4)*8 + j][cb*16 + (lane&15)]
__global__ __launch_bounds__(256) void xk_kernel(
    const float* __restrict__ x, const float* __restrict__ kern,
    unsigned short* __restrict__ bfrag, unsigned short* __restrict__ xk_rm) {
  __shared__ __align__(16) unsigned short kl[FD * FD];
  __shared__ __align__(16) float xl[16 * FD];
  const int t = threadIdx.x;
  const int row0 = blockIdx.x * 16;

  #pragma unroll
  for (int j = 0; j < 16; ++j) {
    int idx = (j * 256 + t) * 4;
    f32x4 kv = *(const f32x4*)&kern[idx];
    ushort4v kw;
    #pragma unroll
    for (int q = 0; q < 4; ++q) kw[q] = f2bf(kv[q]);
    *(ushort4v*)&kl[idx] = kw;
  }
  #pragma unroll
  for (int j = 0; j < 2; ++j) {
    int idx = (j * 256 + t) * 4;
    *(f32x4*)&xl[idx] = *(const f32x4*)&x[(size_t)row0 * FD + idx];
  }
  __syncthreads();

  const int r0 = (t >> 5) * 2;
  const int c0 = (t & 31) * 4;
  float acc[2][4] = {};
  #pragma unroll 4
  for (int k = 0; k < FD; ++k) {
    ushort4v kq = *(const ushort4v*)&kl[k * FD + c0];
    float kv[4];
    #pragma unroll
    for (int q = 0; q < 4; ++q) kv[q] = bf2f(kq[q]);
    float x0 = xl[r0 * FD + k];
    float x1 = xl[(r0 + 1) * FD + k];
    #pragma unroll
    for (int q = 0; q < 4; ++q) {
      acc[0][q] += x0 * kv[q];
      acc[1][q] += x1 * kv[q];
    }
  }
  #pragma unroll
  for (int i = 0; i < 2; ++i) {
    const int r = row0 + r0 + i;
    const int kt = r >> 5;
    const int lhi = ((r >> 3) & 3) * 16;
    const int j = r & 7;
    ushort4v ow;
    #pragma unroll
    for (int q = 0; q < 4; ++q) {
      const int c = c0 + q;
      unsigned short bv = f2bf(acc[i][q]);
      ow[q] = bv;
      bfrag[(((size_t)kt * 8 + (c >> 4)) * 64 + (lhi + (c & 15))) * 8 + j] = bv;
    }
    *(ushort4v*)&xk_rm[(size_t)r * FD + c0] = ow;
  }
}

// -------- Kernel 2: split-K MFMA; block = 64 rows x 128 cols x KW slice ----
template <int S>
__global__ __launch_bounds__(256, 4) void gcn_mm(
    const float* __restrict__ adj, const unsigned short* __restrict__ bfrag,
    float* __restrict__ parts, float* __restrict__ rowpart) {
  constexpr int KW = NN / S;
  constexpr int NS = KW / BK;
  __shared__ __align__(16) unsigned short sA[2][BM * LDS_ROW];  // 18.4 KB

  const int t = threadIdx.x;
  const int b = blockIdx.x;
  const int s = b & (S - 1);
  const int g = b / S;
  const int row0 = g * BM;
  const int l = t & 63;
  const int w = t >> 6;

  // ---- staging geometry: wave w stages rows w*16..w*16+15; instr i is 1 KB
  // contiguous (rows w*16+i*4+(l>>4), bytes (l&15)*16).
  const int su = l >> 4;                 // 0..3
  const int sc = l & 15;                 // 0..15 (16B chunk within the row)
  const float* ap = adj + (size_t)(row0 + w * 16 + su) * NN + (size_t)s * KW + sc * 4;
  const int lw = (w * 16 + su) * LDS_ROW + sc * 4;  // LDS base (ushorts) for i=0

  const unsigned short* bp = bfrag + (size_t)l * 8;

  f32x4 Lr[4];
  float rs[4] = {0.f, 0.f, 0.f, 0.f};
  f32x4 acc[4][2] = {};

  // prologue: stage step 0 into buf 0
  #pragma unroll
  for (int i = 0; i < 4; ++i)
    Lr[i] = *(const f32x4*)(ap + (size_t)i * 4 * NN);
  #pragma unroll
  for (int i = 0; i < 4; ++i) {
    ushort4v cw;
    #pragma unroll
    for (int q = 0; q < 4; ++q) cw[q] = f2bf(Lr[i][q]);
    rs[i] += Lr[i][0] + Lr[i][1] + Lr[i][2] + Lr[i][3];
    *(ushort4v*)&sA[0][lw + i * 4 * LDS_ROW] = cw;
  }
  __syncthreads();

  #pragma unroll 2
  for (int st = 0; st < NS; ++st) {
    const int cur = st & 1;
    // 1. issue next A-tile loads (HBM latency hides under compute)
    if (st + 1 < NS) {
      #pragma unroll
      for (int i = 0; i < 4; ++i)
        Lr[i] = *(const f32x4*)(ap + (size_t)i * 4 * NN + (st + 1) * BK);
    }
    // 2. B fragments for both k-halves (contiguous 1KB wave-loads, L2-hot)
    const int ktg = s * (KW / 32) + st * 2;
    ushort8v bF[2][2];
    #pragma unroll
    for (int h = 0; h < 2; ++h)
      #pragma unroll
      for (int ci = 0; ci < 2; ++ci)
        bF[h][ci] = *(const ushort8v*)(bp + (((size_t)(ktg + h) * 8 + (w * 2 + ci)) * 64) * 8);
    // 3. MFMAs: A-frags from LDS (conflict-free padded layout)
    #pragma unroll
    for (int h = 0; h < 2; ++h) {
      #pragma unroll
      for (int rb = 0; rb < 4; ++rb) {
        const int row = rb * 16 + (l & 15);
        short8 aF = *(const short8*)&sA[cur][row * LDS_ROW + h * 32 + (l >> 4) * 8];
        acc[rb][0] = __builtin_amdgcn_mfma_f32_16x16x32_bf16(aF, bF[h][0], acc[rb][0], 0, 0, 0);
        acc[rb][1] = __builtin_amdgcn_mfma_f32_16x16x32_bf16(aF, bF[h][1], acc[rb][1], 0, 0, 0);
      }
    }
    // 4. convert + rowsum + stage into other buffer
    if (st + 1 < NS) {
      #pragma unroll
      for (int i = 0; i < 4; ++i) {
        ushort4v cw;
        #pragma unroll
        for (int q = 0; q < 4; ++q) cw[q] = f2bf(Lr[i][q]);
        rs[i] += Lr[i][0] + Lr[i][1] + Lr[i][2] + Lr[i][3];
        *(ushort4v*)&sA[cur ^ 1][lw + i * 4 * LDS_ROW] = cw;
      }
    }
    __syncthreads();
  }

  // ---- rowsum: reduce over the 16 k-chunk lanes (l&15), rows preserved ----
  #pragma unroll
  for (int i = 0; i < 4; ++i) {
    rs[i] += __shfl_xor(rs[i], 1);
    rs[i] += __shfl_xor(rs[i], 2);
    rs[i] += __shfl_xor(rs[i], 4);
    rs[i] += __shfl_xor(rs[i], 8);
  }
  if (sc == 0) {
    #pragma unroll
    for (int i = 0; i < 4; ++i)
      rowpart[(size_t)s * NN + row0 + w * 16 + i * 4 + su] = rs[i];
  }

  // ---- store f32 partial tile: C/D col = l&15, row = (l>>4)*4 + j ----
  float* pp = parts + ((size_t)s * NN + row0) * FD + w * 32;
  #pragma unroll
  for (int rb = 0; rb < 4; ++rb)
    #pragma unroll
    for (int ci = 0; ci < 2; ++ci)
      #pragma unroll
      for (int j = 0; j < 4; ++j) {
        const int r = rb * 16 + ((l >> 4) << 2) + j;
        pp[(size_t)r * FD + ci * 16 + (l & 15)] = acc[rb][ci][j];
      }
}

// -------- Kernel 3: reduce S partials + epilogue ---------------------------
__global__ __launch_bounds__(256) void gcn_fin(
    const float* __restrict__ parts, const float* __restrict__ rowpart,
    const unsigned short* __restrict__ xk_rm, const float* __restrict__ beta,
    const float* __restrict__ bias, float* __restrict__ out, int S) {
  const int t = threadIdx.x;
  const int r = blockIdx.x * 16 + (t >> 4);
  const int c0 = (t & 15) * 8;

  float rsum = 0.f;
  for (int s = 0; s < S; ++s) rsum += rowpart[(size_t)s * NN + r];
  const float bt = beta[r];
  const float inv = 1.0f / (rsum + bt);

  f32x4 acc0 = {0.f, 0.f, 0.f, 0.f};
  f32x4 acc1 = {0.f, 0.f, 0.f, 0.f};
  for (int s = 0; s < S; ++s) {
    const float* p = parts + ((size_t)s * NN + r) * FD + c0;
    acc0 += *(const f32x4*)p;
    acc1 += *(const f32x4*)(p + 4);
  }
  ushort8v xv = *(const ushort8v*)&xk_rm[(size_t)r * FD + c0];
  f32x4 o0, o1;
  #pragma unroll
  for (int q = 0; q < 4; ++q) {
    o0[q] = (acc0[q] + bt * bf2f(xv[q])) * inv + bias[c0 + q];
    o1[q] = (acc1[q] + bt * bf2f(xv[4 + q])) * inv + bias[c0 + 4 + q];
  }
  *(f32x4*)&out[(size_t)r * FD + c0] = o0;
  *(f32x4*)&out[(size_t)r * FD + c0 + 4] = o1;
}

extern "C" void kernel_launch(void* const* d_in, const int* in_sizes, int n_in,
                              void* d_out, int out_size, void* d_ws, size_t ws_size,
                              hipStream_t stream) {
  const float* x    = (const float*)d_in[0];
  const float* adj  = (const float*)d_in[1];
  const float* kern = (const float*)d_in[2];
  const float* bias = (const float*)d_in[3];
  const float* beta = (const float*)d_in[4];
  float* out = (float*)d_out;

  char* ws = (char*)d_ws;
  unsigned short* bfrag = (unsigned short*)ws;                          // 2 MB
  unsigned short* xk_rm = (unsigned short*)(ws + (size_t)NN * FD * 2);  // 2 MB
  const size_t off_rowpart = (size_t)NN * FD * 4;
  float* rowpart = (float*)(ws + off_rowpart);                          // 256 KB
  const size_t off_parts = off_rowpart + (size_t)8 * NN * 4;
  float* parts = (float*)(ws + off_parts);

  int S = 8;
  while (S > 1 && off_parts + (size_t)S * NN * FD * 4 > ws_size) S >>= 1;

  hipLaunchKernelGGL(xk_kernel, dim3(NN / 16), dim3(256), 0, stream,
                     x, kern, bfrag, xk_rm);

  dim3 blk(256);
  switch (S) {
    case 8: hipLaunchKernelGGL(gcn_mm<8>, dim3(128 * 8), blk, 0, stream, adj, bfrag, parts, rowpart); break;
    case 4: hipLaunchKernelGGL(gcn_mm<4>, dim3(128 * 4), blk, 0, stream, adj, bfrag, parts, rowpart); break;
    case 2: hipLaunchKernelGGL(gcn_mm<2>, dim3(128 * 2), blk, 0, stream, adj, bfrag, parts, rowpart); break;
    default: hipLaunchKernelGGL(gcn_mm<1>, dim3(128), blk, 0, stream, adj, bfrag, parts, rowpart); break;
  }

  hipLaunchKernelGGL(gcn_fin, dim3(NN / 16), dim3(256), 0, stream,
                     parts, rowpart, xk_rm, beta, bias, out, S);
}

// Round 4
// 85.145 us; speedup vs baseline: 1.6079x; 1.1610x over previous
//
#include <hip/hip_runtime.h>

#define NN 8192
#define FD 128
#define BK 64
#define LDSR 72   // ushorts per LDS A row (144 B, 16B-aligned rows, conflict-light)

typedef float f32x4 __attribute__((ext_vector_type(4)));
typedef short short8 __attribute__((ext_vector_type(8)));
typedef unsigned short ushort4v __attribute__((ext_vector_type(4)));
typedef unsigned short ushort8v __attribute__((ext_vector_type(8)));

__device__ __forceinline__ unsigned short f2bf(float f) {
  unsigned int u = __builtin_bit_cast(unsigned int, f);
  u += 0x7fffu + ((u >> 16) & 1u);   // round-to-nearest-even
  return (unsigned short)(u >> 16);
}
__device__ __forceinline__ float bf2f(unsigned short h) {
  unsigned int u = ((unsigned int)h) << 16;
  return __builtin_bit_cast(float, u);
}

// -------- Kernel 1: xk = x@kern (bf16), emitted as MFMA B-fragments + row-major
// bfrag[((kt*8 + cb)*64 + lane)*8 + j] = xk[kt*32 + (lane>>4)*8 + j][cb*16 + (lane&15)]
__global__ __launch_bounds__(256) void xk_kernel(
    const float* __restrict__ x, const float* __restrict__ kern,
    unsigned short* __restrict__ bfrag, unsigned short* __restrict__ xk_rm) {
  __shared__ __align__(16) unsigned short kl[FD * FD];
  __shared__ __align__(16) float xl[16 * FD];
  const int t = threadIdx.x;
  const int row0 = blockIdx.x * 16;

  #pragma unroll
  for (int j = 0; j < 16; ++j) {
    int idx = (j * 256 + t) * 4;
    f32x4 kv = *(const f32x4*)&kern[idx];
    ushort4v kw;
    #pragma unroll
    for (int q = 0; q < 4; ++q) kw[q] = f2bf(kv[q]);
    *(ushort4v*)&kl[idx] = kw;
  }
  #pragma unroll
  for (int j = 0; j < 2; ++j) {
    int idx = (j * 256 + t) * 4;
    *(f32x4*)&xl[idx] = *(const f32x4*)&x[(size_t)row0 * FD + idx];
  }
  __syncthreads();

  const int r0 = (t >> 5) * 2;
  const int c0 = (t & 31) * 4;
  float acc[2][4] = {};
  #pragma unroll 4
  for (int k = 0; k < FD; ++k) {
    ushort4v kq = *(const ushort4v*)&kl[k * FD + c0];
    float kv[4];
    #pragma unroll
    for (int q = 0; q < 4; ++q) kv[q] = bf2f(kq[q]);
    float x0 = xl[r0 * FD + k];
    float x1 = xl[(r0 + 1) * FD + k];
    #pragma unroll
    for (int q = 0; q < 4; ++q) {
      acc[0][q] += x0 * kv[q];
      acc[1][q] += x1 * kv[q];
    }
  }
  #pragma unroll
  for (int i = 0; i < 2; ++i) {
    const int r = row0 + r0 + i;
    const int kt = r >> 5;
    const int lhi = ((r >> 3) & 3) * 16;
    const int j = r & 7;
    ushort4v ow;
    #pragma unroll
    for (int q = 0; q < 4; ++q) {
      const int c = c0 + q;
      unsigned short bv = f2bf(acc[i][q]);
      ow[q] = bv;
      bfrag[(((size_t)kt * 8 + (c >> 4)) * 64 + (lhi + (c & 15))) * 8 + j] = bv;
    }
    *(ushort4v*)&xk_rm[(size_t)r * FD + c0] = ow;
  }
}

// -------- Kernel 2: barrier-free split-K MFMA -------------------------------
// Wave owns 32 rows x 128 cols x (NN/S) K-slice. Wave-private dbuf LDS A-tile.
template <int S>
__global__ __launch_bounds__(256) void gcn_mm(
    const float* __restrict__ adj, const unsigned short* __restrict__ bfrag,
    unsigned short* __restrict__ parts, float* __restrict__ rowpart) {
  constexpr int KW = NN / S;       // K per slot
  constexpr int NS = KW / BK;      // steps per wave
  __shared__ __align__(16) unsigned short sA[4][2][32 * LDSR];  // 36.9 KB

  const int t = threadIdx.x;
  const int l = t & 63;
  const int w = t >> 6;
  const int b = blockIdx.x;
  const int s = b & (S - 1);                    // K-slot == XCD (round-robin)
  const int row0 = (b / S) * 128 + w * 32;      // this wave's 32 rows
  const int kbase = s * KW;

  // load geometry: instr i(0..7), lane l -> row = i*4 + (l>>4), k_f32 = (l&15)*4
  // each instruction reads 1 KB contiguous (4 rows x 256 B).
  const float* ap = adj + (size_t)(row0 + (l >> 4)) * NN + kbase + (l & 15) * 4;
  unsigned short* sw = &sA[w][0][0];
  const int wofs = (l >> 4) * LDSR + (l & 15) * 4;   // ushort offset, + i*4*LDSR
  const unsigned short* bp = bfrag + (size_t)l * 8;

  f32x4 Lr[8];
  f32x4 acc[2][8] = {};
  float rs[8] = {0.f, 0.f, 0.f, 0.f, 0.f, 0.f, 0.f, 0.f};

  // prologue: load + stage step 0 into buf 0
  #pragma unroll
  for (int i = 0; i < 8; ++i)
    Lr[i] = *(const f32x4*)(ap + (size_t)i * 4 * NN);
  #pragma unroll
  for (int i = 0; i < 8; ++i) {
    ushort4v cw;
    #pragma unroll
    for (int q = 0; q < 4; ++q) cw[q] = f2bf(Lr[i][q]);
    rs[i] += Lr[i][0] + Lr[i][1] + Lr[i][2] + Lr[i][3];
    *(ushort4v*)&sw[wofs + i * 4 * LDSR] = cw;
  }

  #pragma unroll 2
  for (int st = 0; st < NS; ++st) {
    const int cur = st & 1;
    // 1. issue next step's A loads (stay queued through the MFMA phase)
    if (st + 1 < NS) {
      #pragma unroll
      for (int i = 0; i < 8; ++i)
        Lr[i] = *(const f32x4*)(ap + (size_t)i * 4 * NN + (st + 1) * BK);
    }
    // 2. MFMA phase: A-frags from wave-private LDS, B-frags 1KB contiguous (L2)
    const int ktg = s * (KW / 32) + st * 2;
    #pragma unroll
    for (int h = 0; h < 2; ++h) {
      const int abase = cur * 32 * LDSR + h * 32 + (l >> 4) * 8;
      short8 aF0 = *(const short8*)&sw[abase + (l & 15) * LDSR];
      short8 aF1 = *(const short8*)&sw[abase + (16 + (l & 15)) * LDSR];
      #pragma unroll
      for (int cb = 0; cb < 8; ++cb) {
        ushort8v Bf = *(const ushort8v*)(bp + (((size_t)(ktg + h) * 8 + cb) << 9));
        acc[0][cb] = __builtin_amdgcn_mfma_f32_16x16x32_bf16(aF0, Bf, acc[0][cb], 0, 0, 0);
        acc[1][cb] = __builtin_amdgcn_mfma_f32_16x16x32_bf16(aF1, Bf, acc[1][cb], 0, 0, 0);
      }
    }
    // 3. convert + rowsum + stage into the other buffer (waits on step st+1 loads)
    if (st + 1 < NS) {
      const int nb = (cur ^ 1) * 32 * LDSR;
      #pragma unroll
      for (int i = 0; i < 8; ++i) {
        ushort4v cw;
        #pragma unroll
        for (int q = 0; q < 4; ++q) cw[q] = f2bf(Lr[i][q]);
        rs[i] += Lr[i][0] + Lr[i][1] + Lr[i][2] + Lr[i][3];
        *(ushort4v*)&sw[nb + wofs + i * 4 * LDSR] = cw;
      }
    }
  }

  // ---- rowsum: reduce over 16 k-chunk lanes; lane (l&15)==0 holds the sum ----
  #pragma unroll
  for (int i = 0; i < 8; ++i) {
    rs[i] += __shfl_xor(rs[i], 1);
    rs[i] += __shfl_xor(rs[i], 2);
    rs[i] += __shfl_xor(rs[i], 4);
    rs[i] += __shfl_xor(rs[i], 8);
  }
  if ((l & 15) == 0) {
    #pragma unroll
    for (int i = 0; i < 8; ++i)
      rowpart[(size_t)s * NN + row0 + i * 4 + (l >> 4)] = rs[i];
  }

  // ---- store bf16 partial tile: C/D col = l&15, row = (l>>4)*4 + j ----
  unsigned short* pp = parts + ((size_t)s * NN + row0) * FD;
  #pragma unroll
  for (int rf = 0; rf < 2; ++rf)
    #pragma unroll
    for (int cb = 0; cb < 8; ++cb)
      #pragma unroll
      for (int j = 0; j < 4; ++j) {
        const int r = rf * 16 + ((l >> 4) << 2) + j;
        pp[(size_t)r * FD + cb * 16 + (l & 15)] = f2bf(acc[rf][cb][j]);
      }
}

// -------- Kernel 3: reduce S partials + epilogue ---------------------------
__global__ __launch_bounds__(256) void gcn_fin(
    const unsigned short* __restrict__ parts, const float* __restrict__ rowpart,
    const unsigned short* __restrict__ xk_rm, const float* __restrict__ beta,
    const float* __restrict__ bias, float* __restrict__ out, int S) {
  const int t = threadIdx.x;
  const int r = blockIdx.x * 16 + (t >> 4);
  const int c0 = (t & 15) * 8;

  float rsum = 0.f;
  for (int s = 0; s < S; ++s) rsum += rowpart[(size_t)s * NN + r];
  const float bt = beta[r];
  const float inv = 1.0f / (rsum + bt);

  float a[8] = {0.f, 0.f, 0.f, 0.f, 0.f, 0.f, 0.f, 0.f};
  for (int s = 0; s < S; ++s) {
    ushort8v pv = *(const ushort8v*)&parts[((size_t)s * NN + r) * FD + c0];
    #pragma unroll
    for (int q = 0; q < 8; ++q) a[q] += bf2f(pv[q]);
  }
  ushort8v xv = *(const ushort8v*)&xk_rm[(size_t)r * FD + c0];
  f32x4 o0, o1;
  #pragma unroll
  for (int q = 0; q < 4; ++q) {
    o0[q] = (a[q] + bt * bf2f(xv[q])) * inv + bias[c0 + q];
    o1[q] = (a[4 + q] + bt * bf2f(xv[4 + q])) * inv + bias[c0 + 4 + q];
  }
  *(f32x4*)&out[(size_t)r * FD + c0] = o0;
  *(f32x4*)&out[(size_t)r * FD + c0 + 4] = o1;
}

extern "C" void kernel_launch(void* const* d_in, const int* in_sizes, int n_in,
                              void* d_out, int out_size, void* d_ws, size_t ws_size,
                              hipStream_t stream) {
  const float* x    = (const float*)d_in[0];
  const float* adj  = (const float*)d_in[1];
  const float* kern = (const float*)d_in[2];
  const float* bias = (const float*)d_in[3];
  const float* beta = (const float*)d_in[4];
  float* out = (float*)d_out;

  char* ws = (char*)d_ws;
  unsigned short* bfrag = (unsigned short*)ws;                          // 2 MB
  unsigned short* xk_rm = (unsigned short*)(ws + (size_t)NN * FD * 2);  // 2 MB
  const size_t off_rowpart = (size_t)NN * FD * 4;
  float* rowpart = (float*)(ws + off_rowpart);                          // 256 KB
  const size_t off_parts = off_rowpart + (size_t)8 * NN * 4;
  unsigned short* parts = (unsigned short*)(ws + off_parts);            // 16 MB @ S=8

  int S = 8;
  while (S > 1 && off_parts + (size_t)S * NN * FD * 2 > ws_size) S >>= 1;

  hipLaunchKernelGGL(xk_kernel, dim3(NN / 16), dim3(256), 0, stream,
                     x, kern, bfrag, xk_rm);

  dim3 blk(256);
  switch (S) {
    case 8: hipLaunchKernelGGL(gcn_mm<8>, dim3(64 * 8), blk, 0, stream, adj, bfrag, parts, rowpart); break;
    case 4: hipLaunchKernelGGL(gcn_mm<4>, dim3(64 * 4), blk, 0, stream, adj, bfrag, parts, rowpart); break;
    case 2: hipLaunchKernelGGL(gcn_mm<2>, dim3(64 * 2), blk, 0, stream, adj, bfrag, parts, rowpart); break;
    default: hipLaunchKernelGGL(gcn_mm<1>, dim3(64), blk, 0, stream, adj, bfrag, parts, rowpart); break;
  }

  hipLaunchKernelGGL(gcn_fin, dim3(NN / 16), dim3(256), 0, stream,
                     parts, rowpart, xk_rm, beta, bias, out, S);
}

// Round 5
// 83.396 us; speedup vs baseline: 1.6417x; 1.0210x over previous
//
#include <hip/hip_runtime.h>

#define NN 8192
#define FD 128
#define BK 64
#define LDSR 72   // ushorts per LDS A row (144 B, 16B-aligned rows, conflict-light)

typedef float f32x4 __attribute__((ext_vector_type(4)));
typedef short short8 __attribute__((ext_vector_type(8)));
typedef unsigned short ushort4v __attribute__((ext_vector_type(4)));
typedef unsigned short ushort8v __attribute__((ext_vector_type(8)));

__device__ __forceinline__ unsigned short f2bf(float f) {
  unsigned int u = __builtin_bit_cast(unsigned int, f);
  u += 0x7fffu + ((u >> 16) & 1u);   // round-to-nearest-even
  return (unsigned short)(u >> 16);
}
__device__ __forceinline__ float bf2f(unsigned short h) {
  unsigned int u = ((unsigned int)h) << 16;
  return __builtin_bit_cast(float, u);
}

// -------- Kernel 1: xk = x@kern (bf16), emitted as MFMA B-fragments + row-major
// bfrag[((kt*8 + cb)*64 + lane)*8 + j] = xk[kt*32 + (lane>>4)*8 + j][cb*16 + (lane&15)]
__global__ __launch_bounds__(256) void xk_kernel(
    const float* __restrict__ x, const float* __restrict__ kern,
    unsigned short* __restrict__ bfrag, unsigned short* __restrict__ xk_rm) {
  __shared__ __align__(16) unsigned short kl[FD * FD];
  __shared__ __align__(16) float xl[16 * FD];
  const int t = threadIdx.x;
  const int row0 = blockIdx.x * 16;

  #pragma unroll
  for (int j = 0; j < 16; ++j) {
    int idx = (j * 256 + t) * 4;
    f32x4 kv = *(const f32x4*)&kern[idx];
    ushort4v kw;
    #pragma unroll
    for (int q = 0; q < 4; ++q) kw[q] = f2bf(kv[q]);
    *(ushort4v*)&kl[idx] = kw;
  }
  #pragma unroll
  for (int j = 0; j < 2; ++j) {
    int idx = (j * 256 + t) * 4;
    *(f32x4*)&xl[idx] = *(const f32x4*)&x[(size_t)row0 * FD + idx];
  }
  __syncthreads();

  const int r0 = (t >> 5) * 2;
  const int c0 = (t & 31) * 4;
  float acc[2][4] = {};
  #pragma unroll 4
  for (int k = 0; k < FD; ++k) {
    ushort4v kq = *(const ushort4v*)&kl[k * FD + c0];
    float kv[4];
    #pragma unroll
    for (int q = 0; q < 4; ++q) kv[q] = bf2f(kq[q]);
    float x0 = xl[r0 * FD + k];
    float x1 = xl[(r0 + 1) * FD + k];
    #pragma unroll
    for (int q = 0; q < 4; ++q) {
      acc[0][q] += x0 * kv[q];
      acc[1][q] += x1 * kv[q];
    }
  }
  #pragma unroll
  for (int i = 0; i < 2; ++i) {
    const int r = row0 + r0 + i;
    const int kt = r >> 5;
    const int lhi = ((r >> 3) & 3) * 16;
    const int j = r & 7;
    ushort4v ow;
    #pragma unroll
    for (int q = 0; q < 4; ++q) {
      const int c = c0 + q;
      unsigned short bv = f2bf(acc[i][q]);
      ow[q] = bv;
      bfrag[(((size_t)kt * 8 + (c >> 4)) * 64 + (lhi + (c & 15))) * 8 + j] = bv;
    }
    *(ushort4v*)&xk_rm[(size_t)r * FD + c0] = ow;
  }
}

// -------- Kernel 2: barrier-free split-K MFMA, depth-2 pipelined ------------
// Wave owns 32 rows x 128 cols x (NN/S) K-slice. Wave-private dbuf LDS A-tile.
#define PREFETCH(Lr, stp)                                                     \
  do {                                                                        \
    _Pragma("unroll") for (int i = 0; i < 8; ++i)                             \
        Lr[i] = *(const f32x4*)(ap + (size_t)i * 4 * NN + (stp) * BK);        \
  } while (0)

#define STAGE(Lr, bufofs)                                                     \
  do {                                                                        \
    _Pragma("unroll") for (int i = 0; i < 8; ++i) {                           \
      ushort4v cw;                                                            \
      _Pragma("unroll") for (int q = 0; q < 4; ++q) cw[q] = f2bf(Lr[i][q]);   \
      rs[i] += Lr[i][0] + Lr[i][1] + Lr[i][2] + Lr[i][3];                     \
      *(ushort4v*)&sw[(bufofs) + wofs + i * 4 * LDSR] = cw;                   \
    }                                                                         \
  } while (0)

#define MFMA_STEP(stp, bufofs)                                                \
  do {                                                                        \
    const int ktg = kt0 + (stp) * 2;                                          \
    ushort8v Bf[2][8];                                                        \
    _Pragma("unroll") for (int h = 0; h < 2; ++h)                             \
        _Pragma("unroll") for (int cb = 0; cb < 8; ++cb)                      \
            Bf[h][cb] = *(const ushort8v*)(bp +                               \
                (((size_t)(ktg + h) * 8 + cb) << 9));                         \
    __builtin_amdgcn_s_setprio(1);                                            \
    _Pragma("unroll") for (int h = 0; h < 2; ++h) {                           \
      const int abase = (bufofs) + h * 32 + (l >> 4) * 8;                     \
      short8 aF0 = *(const short8*)&sw[abase + (l & 15) * LDSR];              \
      short8 aF1 = *(const short8*)&sw[abase + (16 + (l & 15)) * LDSR];       \
      _Pragma("unroll") for (int cb = 0; cb < 8; ++cb) {                      \
        acc[0][cb] = __builtin_amdgcn_mfma_f32_16x16x32_bf16(                 \
            aF0, Bf[h][cb], acc[0][cb], 0, 0, 0);                             \
        acc[1][cb] = __builtin_amdgcn_mfma_f32_16x16x32_bf16(                 \
            aF1, Bf[h][cb], acc[1][cb], 0, 0, 0);                             \
      }                                                                       \
    }                                                                         \
    __builtin_amdgcn_s_setprio(0);                                            \
  } while (0)

template <int S>
__global__ __launch_bounds__(256, 2) void gcn_mm(
    const float* __restrict__ adj, const unsigned short* __restrict__ bfrag,
    unsigned short* __restrict__ parts, float* __restrict__ rowpart) {
  constexpr int KW = NN / S;       // K per slot
  constexpr int NS = KW / BK;      // steps per wave (16 at S=8)
  __shared__ __align__(16) unsigned short sA[4][2][32 * LDSR];  // 36.9 KB

  const int t = threadIdx.x;
  const int l = t & 63;
  const int w = t >> 6;
  const int b = blockIdx.x;
  const int s = b & (S - 1);                    // K-slot == XCD (round-robin)
  const int row0 = (b / S) * 128 + w * 32;      // this wave's 32 rows
  const int kbase = s * KW;
  const int kt0 = s * (KW / 32);

  // load geometry: instr i(0..7), lane l -> row = i*4 + (l>>4), k_f32 = (l&15)*4
  const float* ap = adj + (size_t)(row0 + (l >> 4)) * NN + kbase + (l & 15) * 4;
  unsigned short* sw = &sA[w][0][0];
  const int wofs = (l >> 4) * LDSR + (l & 15) * 4;
  const int B1OFS = 32 * LDSR;
  const unsigned short* bp = bfrag + (size_t)l * 8;

  f32x4 LrA[8], LrB[8];            // even-step / odd-step register stages
  f32x4 acc[2][8] = {};
  float rs[8] = {0.f, 0.f, 0.f, 0.f, 0.f, 0.f, 0.f, 0.f};

  // prologue
  PREFETCH(LrA, 0);
  STAGE(LrA, 0);                   // step 0 -> buf0
  PREFETCH(LrB, 1);                // step 1 in flight

  for (int st = 0; st < NS; st += 2) {
    if (st + 2 < NS) PREFETCH(LrA, st + 2);    // even prefetch (HBM, early)
    MFMA_STEP(st, 0);                          // consume buf0
    STAGE(LrB, B1OFS);                         // step st+1 -> buf1
    if (st + 3 < NS) PREFETCH(LrB, st + 3);    // odd prefetch
    MFMA_STEP(st + 1, B1OFS);                  // consume buf1
    if (st + 2 < NS) STAGE(LrA, 0);            // step st+2 -> buf0
  }

  // ---- rowsum: reduce over 16 k-chunk lanes; lane (l&15)==0 holds the sum ----
  #pragma unroll
  for (int i = 0; i < 8; ++i) {
    rs[i] += __shfl_xor(rs[i], 1);
    rs[i] += __shfl_xor(rs[i], 2);
    rs[i] += __shfl_xor(rs[i], 4);
    rs[i] += __shfl_xor(rs[i], 8);
  }
  if ((l & 15) == 0) {
    #pragma unroll
    for (int i = 0; i < 8; ++i)
      rowpart[(size_t)s * NN + row0 + i * 4 + (l >> 4)] = rs[i];
  }

  // ---- store bf16 partial tile: C/D col = l&15, row = (l>>4)*4 + j ----
  unsigned short* pp = parts + ((size_t)s * NN + row0) * FD;
  #pragma unroll
  for (int rf = 0; rf < 2; ++rf)
    #pragma unroll
    for (int cb = 0; cb < 8; ++cb)
      #pragma unroll
      for (int j = 0; j < 4; ++j) {
        const int r = rf * 16 + ((l >> 4) << 2) + j;
        pp[(size_t)r * FD + cb * 16 + (l & 15)] = f2bf(acc[rf][cb][j]);
      }
}

// -------- Kernel 3: reduce S partials + epilogue ---------------------------
__global__ __launch_bounds__(256) void gcn_fin(
    const unsigned short* __restrict__ parts, const float* __restrict__ rowpart,
    const unsigned short* __restrict__ xk_rm, const float* __restrict__ beta,
    const float* __restrict__ bias, float* __restrict__ out, int S) {
  const int t = threadIdx.x;
  const int r = blockIdx.x * 16 + (t >> 4);
  const int c0 = (t & 15) * 8;

  float rsum = 0.f;
  for (int s = 0; s < S; ++s) rsum += rowpart[(size_t)s * NN + r];
  const float bt = beta[r];
  const float inv = 1.0f / (rsum + bt);

  float a[8] = {0.f, 0.f, 0.f, 0.f, 0.f, 0.f, 0.f, 0.f};
  for (int s = 0; s < S; ++s) {
    ushort8v pv = *(const ushort8v*)&parts[((size_t)s * NN + r) * FD + c0];
    #pragma unroll
    for (int q = 0; q < 8; ++q) a[q] += bf2f(pv[q]);
  }
  ushort8v xv = *(const ushort8v*)&xk_rm[(size_t)r * FD + c0];
  f32x4 o0, o1;
  #pragma unroll
  for (int q = 0; q < 4; ++q) {
    o0[q] = (a[q] + bt * bf2f(xv[q])) * inv + bias[c0 + q];
    o1[q] = (a[4 + q] + bt * bf2f(xv[4 + q])) * inv + bias[c0 + 4 + q];
  }
  *(f32x4*)&out[(size_t)r * FD + c0] = o0;
  *(f32x4*)&out[(size_t)r * FD + c0 + 4] = o1;
}

extern "C" void kernel_launch(void* const* d_in, const int* in_sizes, int n_in,
                              void* d_out, int out_size, void* d_ws, size_t ws_size,
                              hipStream_t stream) {
  const float* x    = (const float*)d_in[0];
  const float* adj  = (const float*)d_in[1];
  const float* kern = (const float*)d_in[2];
  const float* bias = (const float*)d_in[3];
  const float* beta = (const float*)d_in[4];
  float* out = (float*)d_out;

  char* ws = (char*)d_ws;
  unsigned short* bfrag = (unsigned short*)ws;                          // 2 MB
  unsigned short* xk_rm = (unsigned short*)(ws + (size_t)NN * FD * 2);  // 2 MB
  const size_t off_rowpart = (size_t)NN * FD * 4;
  float* rowpart = (float*)(ws + off_rowpart);                          // 256 KB
  const size_t off_parts = off_rowpart + (size_t)8 * NN * 4;
  unsigned short* parts = (unsigned short*)(ws + off_parts);            // 16 MB @ S=8

  int S = 8;
  while (S > 1 && off_parts + (size_t)S * NN * FD * 2 > ws_size) S >>= 1;

  hipLaunchKernelGGL(xk_kernel, dim3(NN / 16), dim3(256), 0, stream,
                     x, kern, bfrag, xk_rm);

  dim3 blk(256);
  switch (S) {
    case 8: hipLaunchKernelGGL(gcn_mm<8>, dim3(64 * 8), blk, 0, stream, adj, bfrag, parts, rowpart); break;
    case 4: hipLaunchKernelGGL(gcn_mm<4>, dim3(64 * 4), blk, 0, stream, adj, bfrag, parts, rowpart); break;
    case 2: hipLaunchKernelGGL(gcn_mm<2>, dim3(64 * 2), blk, 0, stream, adj, bfrag, parts, rowpart); break;
    default: hipLaunchKernelGGL(gcn_mm<1>, dim3(64), blk, 0, stream, adj, bfrag, parts, rowpart); break;
  }

  hipLaunchKernelGGL(gcn_fin, dim3(NN / 16), dim3(256), 0, stream,
                     parts, rowpart, xk_rm, beta, bias, out, S);
}